// Round 11
// baseline (126.297 us; speedup 1.0000x reference)
//
#include <hip/hip_runtime.h>

#define NH 8
#define HD 16
#define SLEN 1024
#define BATCH 4
#define MAXL 500
#define NSEG 8
#define KTILES_PER_SEG 4

typedef float f32x4  __attribute__((ext_vector_type(4)));
typedef float f32x16 __attribute__((ext_vector_type(16)));
typedef short s16x8  __attribute__((ext_vector_type(8)));
typedef short s16x4  __attribute__((ext_vector_type(4)));

#if defined(__has_builtin)
#if __has_builtin(__builtin_amdgcn_mfma_f32_32x32x8bf16_1k)
#define HAS_PV_REG 1
#endif
#endif
#ifndef HAS_PV_REG
#define HAS_PV_REG 0
#endif

__device__ inline ushort f2bf(float f) {
    uint u = __builtin_bit_cast(uint, f);
    u = (u + 0x7fffu + ((u >> 16) & 1u)) >> 16;
    return (ushort)u;
}
__device__ inline float bf2f(ushort h) {
    uint u = ((uint)h) << 16;
    return __builtin_bit_cast(float, u);
}

// ============ K1: one-shot f32 -> bf16 conversion of all GEMM operands ============
__global__ __launch_bounds__(256) void prep_bf16(
    const float* __restrict__ xq, const float* __restrict__ xk, const float* __restrict__ xv,
    const float* __restrict__ Wq, const float* __restrict__ Wk,
    const float* __restrict__ Wv, const float* __restrict__ Wo,
    const float* __restrict__ emb,
    ushort* __restrict__ xqb, ushort* __restrict__ xkb, ushort* __restrict__ xvb,
    ushort* __restrict__ wqb, ushort* __restrict__ wkb,
    ushort* __restrict__ wvb, ushort* __restrict__ wob,
    ushort* __restrict__ embb)
{
    const int XTOT = 3 * 524288;
    const int WTOT = 4 * 16384;
    const int ETOT = (2 * MAXL + 1) * 128;   // 128128
    int e0 = (blockIdx.x * 256 + threadIdx.x) * 8;
    const float* src;
    ushort* dst;
    int off;
    if (e0 < XTOT) {
        int which = e0 >> 19; off = e0 & 524287;
        src = which == 0 ? xq : which == 1 ? xk : xv;
        dst = which == 0 ? xqb : which == 1 ? xkb : xvb;
    } else if (e0 < XTOT + WTOT) {
        int t = e0 - XTOT; int which = t >> 14; off = t & 16383;
        src = which == 0 ? Wq : which == 1 ? Wk : which == 2 ? Wv : Wo;
        dst = which == 0 ? wqb : which == 1 ? wkb : which == 2 ? wvb : wob;
    } else if (e0 < XTOT + WTOT + ETOT) {
        off = e0 - XTOT - WTOT; src = emb; dst = embb;
    } else {
        return;
    }
    const float4 a = *(const float4*)&src[off];
    const float4 b = *(const float4*)&src[off + 4];
    ushort tmp[8] = {f2bf(a.x), f2bf(a.y), f2bf(a.z), f2bf(a.w),
                     f2bf(b.x), f2bf(b.y), f2bf(b.z), f2bf(b.w)};
    *(s16x8*)&dst[off] = *(const s16x8*)tmp;
}

// ============ K2: QKV projection — LDS-free 1-wave MFMA GEMM ============
__global__ __launch_bounds__(64) void qkv_gemm(
    const ushort* __restrict__ xqb, const ushort* __restrict__ xkb, const ushort* __restrict__ xvb,
    const ushort* __restrict__ wqb, const ushort* __restrict__ wkb, const ushort* __restrict__ wvb,
    const float* __restrict__ bq, const float* __restrict__ bk, const float* __restrict__ bv,
    ushort* __restrict__ Qh, ushort* __restrict__ Kh, ushort* __restrict__ Vt)
{
    const int mode = blockIdx.y;
    const ushort* X = mode == 0 ? xqb : mode == 1 ? xkb : xvb;
    const ushort* W = mode == 0 ? wqb : mode == 1 ? wkb : wvb;
    const float* bb = mode == 0 ? bq : mode == 1 ? bk : bv;

    const int l = threadIdx.x;
    const int row = l & 15, kh = l >> 4;
    const int mt = blockIdx.x >> 2, nq = blockIdx.x & 3;
    const int m0 = mt * 32, n0 = nq * 32;

    s16x8 af[2][4], bfr[2][4];
    #pragma unroll
    for (int ms = 0; ms < 2; ++ms)
        #pragma unroll
        for (int ki = 0; ki < 4; ++ki)
            af[ms][ki] = *(const s16x8*)&X[(size_t)(m0 + 16*ms + row) * 128 + 32*ki + 8*kh];
    #pragma unroll
    for (int ns = 0; ns < 2; ++ns)
        #pragma unroll
        for (int ki = 0; ki < 4; ++ki)
            bfr[ns][ki] = *(const s16x8*)&W[(size_t)(n0 + 16*ns + row) * 128 + 32*ki + 8*kh];

    f32x4 acc[2][2];
    #pragma unroll
    for (int ms = 0; ms < 2; ++ms)
        #pragma unroll
        for (int ns = 0; ns < 2; ++ns)
            #pragma unroll
            for (int r = 0; r < 4; ++r) acc[ms][ns][r] = 0.f;

    #pragma unroll
    for (int ki = 0; ki < 4; ++ki)
        #pragma unroll
        for (int ms = 0; ms < 2; ++ms)
            #pragma unroll
            for (int ns = 0; ns < 2; ++ns)
                acc[ms][ns] = __builtin_amdgcn_mfma_f32_16x16x32_bf16(af[ms][ki], bfr[ns][ki], acc[ms][ns], 0, 0, 0);

    const float scale = (mode == 1) ? 0.25f : 1.0f;
    const int b = m0 >> 10;
    #pragma unroll
    for (int ns = 0; ns < 2; ++ns) {
        const int n = n0 + 16*ns + row;
        const int hh = n >> 4, d = n & 15;
        const float bias = bb[n];
        #pragma unroll
        for (int ms = 0; ms < 2; ++ms) {
            if (mode == 2) {
                ushort4 pk;
                pk.x = f2bf(acc[ms][ns][0] + bias);
                pk.y = f2bf(acc[ms][ns][1] + bias);
                pk.z = f2bf(acc[ms][ns][2] + bias);
                pk.w = f2bf(acc[ms][ns][3] + bias);
                const int s0 = (m0 & 1023) + 16*ms + kh * 4;
                *(ushort4*)&Vt[((size_t)((b*8 + hh)*16 + d)) * SLEN + s0] = pk;
            } else {
                ushort* dst = (mode == 0) ? Qh : Kh;
                #pragma unroll
                for (int r = 0; r < 4; ++r) {
                    const int mm = m0 + 16*ms + kh * 4 + r;
                    const int s = mm & 1023;
                    dst[((size_t)(b*8 + hh) * SLEN + s) * HD + d] = f2bf((acc[ms][ns][r] + bias) * scale);
                }
            }
        }
    }
}

// ============ K3: fused flash attention — barrier-free, global-fragment, split-k x8 ====
// grid (8 qgroups, 32 bh, 8 kseg); 256 thr = 4 independent waves; wave = 32 q rows.
__global__ __launch_bounds__(256) void attn_mfma(
    const ushort* __restrict__ Qh, const ushort* __restrict__ Kh,
    const ushort* __restrict__ Vtg, const ushort* __restrict__ emb_bf,
    float* __restrict__ mp, float* __restrict__ lp, float* __restrict__ op)
{
    __shared__ __align__(16) ushort Rl[4][64][36];
    __shared__ float scb[4][32];
#if !HAS_PV_REG
    __shared__ __align__(16) ushort Pl[4][32][40];
#endif

    const int tid = threadIdx.x;
    const int wid = tid >> 6, lane = tid & 63;
    const int hi = lane >> 5, q = lane & 31;
    const int bh = blockIdx.y, h = bh & 7;
    const int q0b = blockIdx.x * 128;
    const int q0w = q0b + wid * 32;
    const int seg = blockIdx.z;

    const s16x8 qf = *(const s16x8*)&Qh[((size_t)bh * SLEN + q0w + q) * HD + 8 * hi];

    // bias constants for fully-clamped tiles: Q[q] . E[+500], Q[q] . E[-500]
    float cq_hi = 0.f, cq_lo = 0.f;
    {
        const s16x8 ehi = *(const s16x8*)&emb_bf[(size_t)(2 * MAXL) * 128 + h * HD + 8 * hi];
        const s16x8 elo = *(const s16x8*)&emb_bf[h * HD + 8 * hi];
        #pragma unroll
        for (int j = 0; j < 8; ++j) {
            cq_hi += bf2f((ushort)qf[j]) * bf2f((ushort)ehi[j]);
            cq_lo += bf2f((ushort)qf[j]) * bf2f((ushort)elo[j]);
        }
        cq_hi += __shfl_xor(cq_hi, 32);
        cq_lo += __shfl_xor(cq_lo, 32);
    }

#if HAS_PV_REG
    f32x16 acc;
    #pragma unroll
    for (int i = 0; i < 16; ++i) acc[i] = 0.f;
#else
    f32x4 o0, o1;
    #pragma unroll
    for (int r = 0; r < 4; ++r) { o0[r] = 0.f; o1[r] = 0.f; }
#endif
    float m = -1e30f, l = 0.f;

    for (int kt = seg * KTILES_PER_SEG; kt < (seg + 1) * KTILES_PER_SEG; ++kt) {
        const int k0 = kt * 32;
        const int relbase = k0 - q0b - 127;
        const bool clampHi = (relbase >= MAXL);
        const bool clampLo = (relbase + 159 <= -MAXL);

        // --- QK^T (swapped): sa = S^T[krow][q]; K fragment direct from global ---
        const s16x8 kf = *(const s16x8*)&Kh[((size_t)bh * SLEN + k0 + q) * HD + 8 * hi];
        f32x16 sa;
        #pragma unroll
        for (int i = 0; i < 16; ++i) sa[i] = 0.f;
        sa = __builtin_amdgcn_mfma_f32_32x32x16_bf16(kf, qf, sa, 0, 0, 0);

        float p[16];
        if (!(clampHi || clampLo)) {
            // --- R GEMM: E rows direct from global (clamped per lane) ---
            const int j0w = 96 - 32 * wid;
            #pragma unroll
            for (int st = 0; st < 2; ++st) {
                int rel = relbase + j0w + 32 * st + q;
                rel = rel < -MAXL ? -MAXL : (rel > MAXL ? MAXL : rel);
                const s16x8 ef = *(const s16x8*)&emb_bf[(size_t)(rel + MAXL) * 128 + h * HD + 8 * hi];
                f32x16 ra;
                #pragma unroll
                for (int i = 0; i < 16; ++i) ra[i] = 0.f;
                ra = __builtin_amdgcn_mfma_f32_32x32x16_bf16(qf, ef, ra, 0, 0, 0);
                #pragma unroll
                for (int g = 0; g < 4; ++g) {
                    ushort4 pk;
                    pk.x = f2bf(ra[4*g + 0]); pk.y = f2bf(ra[4*g + 1]);
                    pk.z = f2bf(ra[4*g + 2]); pk.w = f2bf(ra[4*g + 3]);
                    *(ushort4*)&Rl[wid][32*st + q][8*g + 4*hi] = pk;
                }
            }
            #pragma unroll
            for (int r = 0; r < 16; ++r) {
                const int krow = (r & 3) + 8 * (r >> 2) + 4 * hi;
                p[r] = sa[r] + bf2f(Rl[wid][krow - q + 31][q]);
            }
        } else {
            const float cq = clampHi ? cq_hi : cq_lo;
            #pragma unroll
            for (int r = 0; r < 16; ++r) p[r] = sa[r] + cq;
        }

        // --- online softmax (lane owns q-row halves; merge across hi via shfl) ---
        float tm = -1e30f;
        #pragma unroll
        for (int r = 0; r < 16; ++r) tm = fmaxf(tm, p[r]);
        tm = fmaxf(tm, __shfl_xor(tm, 32));
        const float mn = fmaxf(m, tm);
        const float scf = __expf(m - mn);
        float ls = 0.f;
        #pragma unroll
        for (int r = 0; r < 16; ++r) { p[r] = __expf(p[r] - mn); ls += p[r]; }
        ls += __shfl_xor(ls, 32);
        l = l * scf + ls;
        m = mn;
        scb[wid][q] = scf;

#if HAS_PV_REG
        // --- rescale acc rows, then PV via 4x mfma_32x32x8 with A = p regs ---
        #pragma unroll
        for (int r = 0; r < 16; ++r) acc[r] *= scb[wid][(r & 3) + 8 * (r >> 2) + 4 * hi];
        const int d = lane & 15;
        __builtin_amdgcn_s_setprio(1);
        #pragma unroll
        for (int s = 0; s < 4; ++s) {
            ushort pk4[4] = {f2bf(p[4*s + 0]), f2bf(p[4*s + 1]),
                             f2bf(p[4*s + 2]), f2bf(p[4*s + 3])};
            const s16x4 ap = *(const s16x4*)pk4;
            const s16x4 vb = *(const s16x4*)&Vtg[((size_t)(bh * 16 + d)) * SLEN + k0 + 8*s + 4*hi];
            acc = __builtin_amdgcn_mfma_f32_32x32x8bf16_1k(ap, vb, acc, 0, 0, 0);
        }
        __builtin_amdgcn_s_setprio(0);
#else
        // --- fallback: Pl LDS round-trip + 2x mfma_16x16x32 (R9 path) ---
        #pragma unroll
        for (int g = 0; g < 4; ++g) {
            ushort4 pk;
            pk.x = f2bf(p[4*g + 0]); pk.y = f2bf(p[4*g + 1]);
            pk.z = f2bf(p[4*g + 2]); pk.w = f2bf(p[4*g + 3]);
            *(ushort4*)&Pl[wid][q][8*g + 4*hi] = pk;
        }
        const s16x8 vf = *(const s16x8*)&Vtg[((size_t)(bh * 16 + (lane & 15))) * SLEN + k0 + 8 * (lane >> 4)];
        {
            const s16x8 pa = *(const s16x8*)&Pl[wid][lane & 15][8 * (lane >> 4)];
            #pragma unroll
            for (int r = 0; r < 4; ++r) o0[r] *= scb[wid][(lane >> 4) * 4 + r];
            o0 = __builtin_amdgcn_mfma_f32_16x16x32_bf16(pa, vf, o0, 0, 0, 0);
        }
        {
            const s16x8 pa = *(const s16x8*)&Pl[wid][16 + (lane & 15)][8 * (lane >> 4)];
            #pragma unroll
            for (int r = 0; r < 4; ++r) o1[r] *= scb[wid][16 + (lane >> 4) * 4 + r];
            o1 = __builtin_amdgcn_mfma_f32_16x16x32_bf16(pa, vf, o1, 0, 0, 0);
        }
#endif
    }

    // --- write raw partials (no normalize) ---
    const size_t pbase = (size_t)(seg * 32 + bh) * SLEN;
    if (hi == 0) {
        mp[pbase + q0w + q] = m;
        lp[pbase + q0w + q] = l;
    }
#if HAS_PV_REG
    if ((lane & 31) < 16) {
        const int d = lane & 31;
        #pragma unroll
        for (int r = 0; r < 16; ++r) {
            const int qp = (r & 3) + 8 * (r >> 2) + 4 * hi;
            op[(pbase + q0w + qp) * HD + d] = acc[r];
        }
    }
#else
    #pragma unroll
    for (int half = 0; half < 2; ++half) {
        #pragma unroll
        for (int r = 0; r < 4; ++r) {
            const int qp = half * 16 + (lane >> 4) * 4 + r;
            op[(pbase + q0w + qp) * HD + (lane & 15)] = (half ? o1[r] : o0[r]);
        }
    }
#endif
}

// ============ K4: split-k merge -> bf16 ohbf[b*S+q][h*16+d] ============
__global__ __launch_bounds__(256) void merge_kernel(
    const float* __restrict__ mp, const float* __restrict__ lp,
    const float* __restrict__ op, ushort* __restrict__ ohbf)
{
    const int idx = blockIdx.x * 256 + threadIdx.x;
    const int d = idx & 15;
    const int row = idx >> 4;                          // bh*1024 + q
    const int bh = row >> 10, q = row & 1023;
    const int h = bh & 7, b = bh >> 3;

    float ms[NSEG];
    float M = -1e30f;
    #pragma unroll
    for (int s = 0; s < NSEG; ++s) {
        ms[s] = mp[(size_t)s * 32 * SLEN + row];
        M = fmaxf(M, ms[s]);
    }
    float L = 0.f, acc = 0.f;
    #pragma unroll
    for (int s = 0; s < NSEG; ++s) {
        const float w = __expf(ms[s] - M);
        L += lp[(size_t)s * 32 * SLEN + row] * w;
        acc += op[((size_t)s * 32 * SLEN + row) * HD + d] * w;
    }
    ohbf[((size_t)(b * SLEN + q)) * 128 + h * HD + d] = f2bf(acc / L);
}

// ============ K5: output projection — LDS-free 1-wave MFMA GEMM, f32 out ============
__global__ __launch_bounds__(64) void out_gemm(
    const ushort* __restrict__ ohbf, const ushort* __restrict__ wob,
    const float* __restrict__ bo, float* __restrict__ out)
{
    const int l = threadIdx.x;
    const int row = l & 15, kh = l >> 4;
    const int mt = blockIdx.x >> 2, nq = blockIdx.x & 3;
    const int m0 = mt * 32, n0 = nq * 32;

    s16x8 af[2][4], bfr[2][4];
    #pragma unroll
    for (int ms = 0; ms < 2; ++ms)
        #pragma unroll
        for (int ki = 0; ki < 4; ++ki)
            af[ms][ki] = *(const s16x8*)&ohbf[(size_t)(m0 + 16*ms + row) * 128 + 32*ki + 8*kh];
    #pragma unroll
    for (int ns = 0; ns < 2; ++ns)
        #pragma unroll
        for (int ki = 0; ki < 4; ++ki)
            bfr[ns][ki] = *(const s16x8*)&wob[(size_t)(n0 + 16*ns + row) * 128 + 32*ki + 8*kh];

    f32x4 acc[2][2];
    #pragma unroll
    for (int ms = 0; ms < 2; ++ms)
        #pragma unroll
        for (int ns = 0; ns < 2; ++ns)
            #pragma unroll
            for (int r = 0; r < 4; ++r) acc[ms][ns][r] = 0.f;

    #pragma unroll
    for (int ki = 0; ki < 4; ++ki)
        #pragma unroll
        for (int ms = 0; ms < 2; ++ms)
            #pragma unroll
            for (int ns = 0; ns < 2; ++ns)
                acc[ms][ns] = __builtin_amdgcn_mfma_f32_16x16x32_bf16(af[ms][ki], bfr[ns][ki], acc[ms][ns], 0, 0, 0);

    #pragma unroll
    for (int ns = 0; ns < 2; ++ns) {
        const int n = n0 + 16*ns + row;
        const float bias = bo[n];
        #pragma unroll
        for (int ms = 0; ms < 2; ++ms)
            #pragma unroll
            for (int r = 0; r < 4; ++r) {
                const int mm = m0 + 16*ms + kh * 4 + r;
                out[(size_t)mm * 128 + n] = acc[ms][ns][r] + bias;
            }
    }
}

extern "C" void kernel_launch(void* const* d_in, const int* in_sizes, int n_in,
                              void* d_out, int out_size, void* d_ws, size_t ws_size,
                              hipStream_t stream)
{
    const float* query  = (const float*)d_in[0];
    const float* key_in = (const float*)d_in[1];
    const float* value  = (const float*)d_in[2];
    const float* Wq = (const float*)d_in[3];
    const float* bq = (const float*)d_in[4];
    const float* Wk = (const float*)d_in[5];
    const float* bk = (const float*)d_in[6];
    const float* Wv = (const float*)d_in[7];
    const float* bv = (const float*)d_in[8];
    const float* Wo = (const float*)d_in[9];
    const float* bo = (const float*)d_in[10];
    const float* emb = (const float*)d_in[11];
    float* out = (float*)d_out;

    const size_t TEN = (size_t)BATCH * NH * SLEN * HD;      // 524288
    const size_t WE  = 16384;
    const size_t EE  = (size_t)(2 * MAXL + 1) * 128;        // 128128
    const size_t ROWS = (size_t)32 * SLEN;                  // 32768

    ushort* qh   = (ushort*)d_ws;
    ushort* kh   = qh + TEN;
    ushort* vtg  = kh + TEN;
    ushort* xqb  = vtg + TEN;
    ushort* xkb  = xqb + TEN;
    ushort* xvb  = xkb + TEN;
    ushort* wqb  = xvb + TEN;
    ushort* wkb  = wqb + WE;
    ushort* wvb  = wkb + WE;
    ushort* wob  = wvb + WE;
    ushort* embb = wob + WE;
    ushort* ohbf = embb + EE;
    float*  mp   = (float*)(ohbf + TEN);
    float*  lp   = mp + NSEG * ROWS;
    float*  op   = lp + NSEG * ROWS;                        // NSEG*ROWS*16 f32

    prep_bf16<<<863, 256, 0, stream>>>(query, key_in, value, Wq, Wk, Wv, Wo, emb,
                                       xqb, xkb, xvb, wqb, wkb, wvb, wob, embb);
    qkv_gemm<<<dim3(512, 3), 64, 0, stream>>>(xqb, xkb, xvb, wqb, wkb, wvb,
                                              bq, bk, bv, qh, kh, vtg);
    attn_mfma<<<dim3(8, 32, NSEG), 256, 0, stream>>>(qh, kh, vtg, embb, mp, lp, op);
    merge_kernel<<<(32 * SLEN * HD) / 256, 256, 0, stream>>>(mp, lp, op, ohbf);
    out_gemm<<<512, 64, 0, stream>>>(ohbf, wob, bo, out);
}